// Round 8
// baseline (454.402 us; speedup 1.0000x reference)
//
#include <hip/hip_runtime.h>
#include <math.h>

#define N_SEQ 20000
#define LCH 64
#define NCH 313   // ceil(20000/64)
#define NB7 79    // ceil(20000/256)
#define PF 16     // k5 prefetch depth

#define DOT4(a,b) ((a).x*(b).x + (a).y*(b).y + (a).z*(b).z + (a).w*(b).w)

typedef __attribute__((ext_vector_type(8))) short short8b;   // 8 bf16 (4 VGPR)
typedef __attribute__((ext_vector_type(4))) float f32x4;

__device__ __forceinline__ float siluf(float v) { return v / (1.f + __expf(-v)); }

__device__ __forceinline__ ushort bf16rne(float f) {
  uint u = __float_as_uint(f);
  return (ushort)((u + 0x7fffu + ((u >> 16) & 1u)) >> 16);
}
__device__ __forceinline__ float bf2f(ushort h) { return __uint_as_float(((uint)h) << 16); }

__device__ __forceinline__ void cvt8(const float4 v0, const float4 v1,
                                     short8b& hi, short8b& lo) {
  float a[8] = {v0.x, v0.y, v0.z, v0.w, v1.x, v1.y, v1.z, v1.w};
  #pragma unroll
  for (int j = 0; j < 8; j++) {
    ushort h = bf16rne(a[j]);
    hi[j] = (short)h;
    lo[j] = (short)bf16rne(a[j] - bf2f(h));
  }
}

// K0: one-time W1 f32 -> bf16 hi/lo planes (64x1024)
__global__ __launch_bounds__(256) void k0_convW(
    const float* __restrict__ W1, ushort* __restrict__ whi, ushort* __restrict__ wlo)
{
  int i = blockIdx.x * 256 + threadIdx.x;   // 65536 elems
  float v = W1[i];
  ushort h = bf16rne(v);
  whi[i] = h;
  wlo[i] = bf16rne(v - bf2f(h));
}

// K1m: partial = x_path[rb:rb+64] @ W1.T over K slice blockIdx.y*256.
// No LDS, no barriers: each lane loads its own MFMA fragments directly.
// A frag: row=lane&15, k=(lane>>4)*8+j (contiguous). B from preconverted planes.
__global__ __launch_bounds__(256) void k1m_mfma(
    const float* __restrict__ xp, const ushort* __restrict__ whi,
    const ushort* __restrict__ wlo, float* __restrict__ part)
{
  const int tid = threadIdx.x;
  const int wv = tid >> 6, lane = tid & 63;
  const int i16 = lane & 15, kb = lane >> 4;
  const int rb = blockIdx.x * 64;
  const int row = rb + wv * 16 + i16;
  const int kbase = blockIdx.y * 256;
  const bool valid = row < N_SEQ;
  const float* asrc = xp + (size_t)row * 1024 + kbase + kb * 8;
  const ushort* bh0 = whi + kbase + kb * 8;
  const ushort* bl0 = wlo + kbase + kb * 8;

  f32x4 acc[4];
  #pragma unroll
  for (int nt = 0; nt < 4; nt++) acc[nt] = (f32x4){0.f, 0.f, 0.f, 0.f};

  #pragma unroll 2
  for (int ks = 0; ks < 8; ks++) {
    short8b ahf, alf;
    if (valid) {
      float4 v0 = *(const float4*)&asrc[ks * 32 + 0];
      float4 v1 = *(const float4*)&asrc[ks * 32 + 4];
      cvt8(v0, v1, ahf, alf);
    } else {
      #pragma unroll
      for (int j = 0; j < 8; j++) { ahf[j] = 0; alf[j] = 0; }
    }
    #pragma unroll
    for (int nt = 0; nt < 4; nt++) {
      const size_t boff = (size_t)(nt * 16 + i16) * 1024 + ks * 32;
      short8b bhf = *(const short8b*)&bh0[boff];
      short8b blf = *(const short8b*)&bl0[boff];
      acc[nt] = __builtin_amdgcn_mfma_f32_16x16x32_bf16(ahf, bhf, acc[nt], 0, 0, 0);
      acc[nt] = __builtin_amdgcn_mfma_f32_16x16x32_bf16(ahf, blf, acc[nt], 0, 0, 0);
      acc[nt] = __builtin_amdgcn_mfma_f32_16x16x32_bf16(alf, bhf, acc[nt], 0, 0, 0);
    }
  }
  // D: row (in wave M-tile) = kb*4 + r, col = nt*16 + i16
  float* pb = part + blockIdx.y * 1280000;
  #pragma unroll
  for (int nt = 0; nt < 4; nt++)
    #pragma unroll
    for (int r = 0; r < 4; r++) {
      int n = rb + wv * 16 + kb * 4 + r;
      if (n < N_SEQ) pb[n * 64 + nt * 16 + i16] = acc[nt][r];
    }
}

// K2f: feature = relu(sum of 4 partials + b1) (written out + staged in LDS),
//      then xz = feature @ in_proj_w.T over 4 column tiles -> xz_x, zs=silu(z)
__global__ __launch_bounds__(256) void k2f_inproj(
    const float* __restrict__ part, const float* __restrict__ b1,
    const float* __restrict__ ipw, float* __restrict__ feat,
    float* __restrict__ xz_x, float* __restrict__ zs)
{
  __shared__ float fs[64 * 68];   // [k][row]
  __shared__ float wl[64 * 68];   // [k][col]
  const int tid = threadIdx.x;
  const int rb = blockIdx.x * 64;
  #pragma unroll
  for (int i = 0; i < 16; i++) {
    int idx = tid + i * 256;       // 4096
    int r = idx >> 6, k = idx & 63;
    int n = rb + r;
    float v = 0.f;
    if (n < N_SEQ) {
      v = part[n * 64 + k] + part[1280000 + n * 64 + k]
        + part[2560000 + n * 64 + k] + part[3840000 + n * 64 + k] + b1[k];
      v = fmaxf(v, 0.f);
      feat[n * 64 + k] = v;
    }
    fs[k * 68 + r] = v;
  }
  const int tr = tid >> 4, tc = tid & 15;
  for (int cb = 0; cb < 4; cb++) {
    __syncthreads();   // fs ready (cb=0) / previous GEMM done with wl
    #pragma unroll
    for (int i = 0; i < 16; i++) {
      int idx = tid + i * 256;
      int c = idx >> 6, k = idx & 63;
      wl[k * 68 + c] = ipw[(cb * 64 + c) * 64 + k];
    }
    __syncthreads();
    float acc[4][4] = {};
    for (int kh = 0; kh < 64; kh += 32) {
      #pragma unroll
      for (int k2 = 0; k2 < 32; k2++) {
        int k = kh + k2;
        float4 xv = *(const float4*)&fs[k * 68 + tr * 4];
        float4 wv = *(const float4*)&wl[k * 68 + tc * 4];
        acc[0][0] += xv.x*wv.x; acc[0][1] += xv.x*wv.y; acc[0][2] += xv.x*wv.z; acc[0][3] += xv.x*wv.w;
        acc[1][0] += xv.y*wv.x; acc[1][1] += xv.y*wv.y; acc[1][2] += xv.y*wv.z; acc[1][3] += xv.y*wv.w;
        acc[2][0] += xv.z*wv.x; acc[2][1] += xv.z*wv.y; acc[2][2] += xv.z*wv.z; acc[2][3] += xv.z*wv.w;
        acc[3][0] += xv.w*wv.x; acc[3][1] += xv.w*wv.y; acc[3][2] += xv.w*wv.z; acc[3][3] += xv.w*wv.w;
      }
    }
    const int cc = cb * 64 + tc * 4;
    #pragma unroll
    for (int i = 0; i < 4; i++) {
      int n = rb + tr * 4 + i;
      if (n < N_SEQ) {
        if (cc < 128) {
          float4 o = {acc[i][0], acc[i][1], acc[i][2], acc[i][3]};
          *(float4*)&xz_x[n * 128 + cc] = o;
        } else {
          float4 o = {siluf(acc[i][0]), siluf(acc[i][1]), siluf(acc[i][2]), siluf(acc[i][3])};
          *(float4*)&zs[n * 128 + cc - 128] = o;
        }
      }
    }
  }
}

// K3: causal depthwise conv + silu -> xc ; x_dbl = xc @ x_proj_w.T -> dt_raw,B,C ;
//     dt = softplus(dt_raw @ dt_proj_w.T + dt_proj_b)   [512 threads]
__global__ __launch_bounds__(512) void k3_conv_proj(
    const float* __restrict__ xz_x, const float* __restrict__ cw,
    const float* __restrict__ cb, const float* __restrict__ xpw,
    const float* __restrict__ dtw, const float* __restrict__ dtb,
    float* __restrict__ xc, float* __restrict__ dt,
    float* __restrict__ Bm, float* __restrict__ Cm)
{
  __shared__ float xzl[51 * 128];
  __shared__ float xcl[48 * 128];
  __shared__ float xwl[36 * 132];
  __shared__ float dtrl[48 * 4];
  const int tid = threadIdx.x;
  const int r0 = blockIdx.x * 48;
  for (int idx = tid; idx < 51 * 128; idx += 512) {
    int rg = r0 - 3 + (idx >> 7);
    int c = idx & 127;
    xzl[idx] = (rg >= 0 && rg < N_SEQ) ? xz_x[rg * 128 + c] : 0.f;
  }
  for (int idx = tid; idx < 36 * 128; idx += 512) {
    int j = idx >> 7, c = idx & 127;
    xwl[j * 132 + c] = xpw[idx];
  }
  __syncthreads();
  const int c = tid & 127;
  const int rbase = tid >> 7;  // 0..3
  const float4 cw4 = *(const float4*)&cw[c * 4];
  const float cbv = cb[c];
  #pragma unroll
  for (int i = 0; i < 12; i++) {
    int rl = rbase + 4 * i;
    float v = cw4.x * xzl[(rl+0)*128 + c] + cw4.y * xzl[(rl+1)*128 + c]
            + cw4.z * xzl[(rl+2)*128 + c] + cw4.w * xzl[(rl+3)*128 + c] + cbv;
    v = siluf(v);
    xcl[rl * 128 + c] = v;
    int n = r0 + rl;
    if (n < N_SEQ) xc[n * 128 + c] = v;
  }
  __syncthreads();
  for (int idx = tid; idx < 48 * 36; idx += 512) {
    int r = idx / 36, j = idx - r * 36;
    float s = 0.f;
    #pragma unroll
    for (int k = 0; k < 128; k += 4) {
      float4 a = *(const float4*)&xcl[r * 128 + k];
      float4 b = *(const float4*)&xwl[j * 132 + k];
      s += DOT4(a, b);
    }
    int n = r0 + r;
    if (j < 4) dtrl[r * 4 + j] = s;
    else if (n < N_SEQ) {
      if (j < 20) Bm[n * 16 + (j - 4)] = s;
      else        Cm[n * 16 + (j - 20)] = s;
    }
  }
  __syncthreads();
  const float4 dw4 = *(const float4*)&dtw[c * 4];
  const float dbv = dtb[c];
  #pragma unroll
  for (int i = 0; i < 12; i++) {
    int rl = rbase + 4 * i;
    int n = r0 + rl;
    if (n < N_SEQ) {
      float4 dr = *(const float4*)&dtrl[rl * 4];
      float v = DOT4(dr, dw4) + dbv;
      dt[n * 128 + c] = (v > 20.f) ? v : log1pf(__expf(v));
    }
  }
}

// K4 (phase A): per-chunk P and local scan end, LDS chunk-staged (16 rows/chunk, dbuf)
__global__ __launch_bounds__(512) void k4_scanA(
    const float* __restrict__ dt, const float* __restrict__ xc,
    const float* __restrict__ Bm, const float* __restrict__ Alog,
    float* __restrict__ Pb, float* __restrict__ he)
{
  __shared__ float sdt[2][2048];
  __shared__ float sxc[2][2048];
  __shared__ float sB[2][256];
  const int t = threadIdx.x;
  const int chunk = blockIdx.x;
  const int n0 = chunk * LCH;
  const int srow = t >> 5, scol = (t & 31) * 4;
  const int c = t >> 2, sq = t & 3;
  float4 al = *(const float4*)&Alog[t * 4];
  const float A0 = -__expf(al.x), A1 = -__expf(al.y), A2 = -__expf(al.z), A3 = -__expf(al.w);
  float h0=0,h1=0,h2=0,h3=0;
  float p0=1,p1=1,p2=1,p3=1;

  auto stage = [&](int cb, int buf) {
    int n = n0 + cb * 16 + srow;
    float4 vd = {0,0,0,0}, vx = {0,0,0,0};
    if (n < N_SEQ) {
      vd = *(const float4*)&dt[n * 128 + scol];
      vx = *(const float4*)&xc[n * 128 + scol];
    }
    *(float4*)&sdt[buf][srow * 128 + scol] = vd;
    *(float4*)&sxc[buf][srow * 128 + scol] = vx;
    if (t < 64) {
      int br = t >> 2, bq = (t & 3) * 4;
      int nb = n0 + cb * 16 + br;
      float4 vb = {0,0,0,0};
      if (nb < N_SEQ) vb = *(const float4*)&Bm[nb * 16 + bq];
      *(float4*)&sB[buf][br * 16 + bq] = vb;
    }
  };

  stage(0, 0);
  __syncthreads();
  int cur = 0;
  for (int cb = 0; cb < 4; cb++) {
    if (cb + 1 < 4) stage(cb + 1, cur ^ 1);
    #pragma unroll
    for (int rl = 0; rl < 16; rl++) {
      float dtv = sdt[cur][rl * 128 + c];
      float xv  = sxc[cur][rl * 128 + c];
      float4 Bv = *(const float4*)&sB[cur][rl * 16 + sq * 4];
      float bs = dtv * xv;
      float e0 = __expf(dtv*A0), e1 = __expf(dtv*A1), e2 = __expf(dtv*A2), e3 = __expf(dtv*A3);
      h0 = e0*h0 + bs*Bv.x; h1 = e1*h1 + bs*Bv.y; h2 = e2*h2 + bs*Bv.z; h3 = e3*h3 + bs*Bv.w;
      p0 *= e0; p1 *= e1; p2 *= e2; p3 *= e3;
    }
    __syncthreads();
    cur ^= 1;
  }
  const int base = chunk * 2048 + t * 4;
  float4 P4 = {p0,p1,p2,p3}; *(float4*)&Pb[base] = P4;
  float4 H4 = {h0,h1,h2,h3}; *(float4*)&he[base] = H4;
}

// K5 (phase B): sequential carry over chunks, 8 blocks x 256 threads, 16-deep prefetch.
// NOTE: hi aliases Pb — no __restrict__ here so program-order load/store is kept.
__global__ __launch_bounds__(256) void k5_carry(
    const float* Pb, const float* he, float* hi)
{
  const int q = blockIdx.x * 256 + threadIdx.x;   // chain id, 0..2047
  float pr[PF], er[PF];
  #pragma unroll
  for (int j = 0; j < PF; j++) {
    pr[j] = Pb[j * 2048 + q];
    er[j] = he[j * 2048 + q];
  }
  float h = 0.f;
  for (int k = 0; k < NCH; k += PF) {
    #pragma unroll
    for (int j = 0; j < PF; j++) {
      int kk = k + j;
      if (kk < NCH) {
        hi[kk * 2048 + q] = h;
        h = fmaf(pr[j], h, er[j]);
        int kn = kk + PF;
        if (kn < NCH) {
          pr[j] = Pb[kn * 2048 + q];
          er[j] = he[kn * 2048 + q];
        }
      }
    }
  }
}

// K6 (phase C): replay scan with carries, fused ys*C + D-skip + z-gate -> y
__global__ __launch_bounds__(512) void k6_scanC(
    const float* __restrict__ dt, const float* __restrict__ xc,
    const float* __restrict__ Bm, const float* __restrict__ Cm,
    const float* __restrict__ zs, const float* __restrict__ Alog,
    const float* __restrict__ Dsk, const float* __restrict__ hi,
    float* __restrict__ y)
{
  __shared__ float sdt[2][2048];
  __shared__ float sxc[2][2048];
  __shared__ float szs[2][2048];
  __shared__ float sBC[2][512];
  const int t = threadIdx.x;
  const int chunk = blockIdx.x;
  const int n0 = chunk * LCH;
  const int srow = t >> 5, scol = (t & 31) * 4;
  const int c = t >> 2, sq = t & 3;
  float4 al = *(const float4*)&Alog[t * 4];
  const float A0 = -__expf(al.x), A1 = -__expf(al.y), A2 = -__expf(al.z), A3 = -__expf(al.w);
  float4 h4 = *(const float4*)&hi[chunk * 2048 + t * 4];
  float h0 = h4.x, h1 = h4.y, h2 = h4.z, h3 = h4.w;
  const float Dc = Dsk[c];

  auto stage = [&](int cb, int buf) {
    int n = n0 + cb * 16 + srow;
    float4 vd = {0,0,0,0}, vx = {0,0,0,0}, vz = {0,0,0,0};
    if (n < N_SEQ) {
      vd = *(const float4*)&dt[n * 128 + scol];
      vx = *(const float4*)&xc[n * 128 + scol];
      vz = *(const float4*)&zs[n * 128 + scol];
    }
    *(float4*)&sdt[buf][srow * 128 + scol] = vd;
    *(float4*)&sxc[buf][srow * 128 + scol] = vx;
    *(float4*)&szs[buf][srow * 128 + scol] = vz;
    if (t < 128) {
      int sel = t >> 6;           // 0: B, 1: C
      int u = t & 63;
      int br = u >> 2, bq = (u & 3) * 4;
      int nb = n0 + cb * 16 + br;
      float4 v = {0,0,0,0};
      if (nb < N_SEQ) v = sel ? *(const float4*)&Cm[nb * 16 + bq]
                              : *(const float4*)&Bm[nb * 16 + bq];
      *(float4*)&sBC[buf][sel * 256 + br * 16 + bq] = v;
    }
  };

  stage(0, 0);
  __syncthreads();
  int cur = 0;
  for (int cb = 0; cb < 4; cb++) {
    if (cb + 1 < 4) stage(cb + 1, cur ^ 1);
    #pragma unroll
    for (int rl = 0; rl < 16; rl++) {
      float dtv = sdt[cur][rl * 128 + c];
      float xv  = sxc[cur][rl * 128 + c];
      float zv  = szs[cur][rl * 128 + c];
      float4 Bv = *(const float4*)&sBC[cur][rl * 16 + sq * 4];
      float4 Cv = *(const float4*)&sBC[cur][256 + rl * 16 + sq * 4];
      float bs = dtv * xv;
      float e0 = __expf(dtv*A0), e1 = __expf(dtv*A1), e2 = __expf(dtv*A2), e3 = __expf(dtv*A3);
      h0 = e0*h0 + bs*Bv.x; h1 = e1*h1 + bs*Bv.y; h2 = e2*h2 + bs*Bv.z; h3 = e3*h3 + bs*Bv.w;
      float part = h0*Cv.x + h1*Cv.y + h2*Cv.z + h3*Cv.w;
      part += __shfl_xor(part, 1, 64);
      part += __shfl_xor(part, 2, 64);
      int n = n0 + cb * 16 + rl;
      if (sq == 0 && n < N_SEQ) y[n * 128 + c] = (part + Dc * xv) * zv;
    }
    __syncthreads();
    cur ^= 1;
  }
}

// K6b: feat = y @ out_proj_w.T + feature ; es[n]=exp(logit), per-block sums   [512 threads]
__global__ __launch_bounds__(512) void k6b_out_attn(
    const float* __restrict__ y, const float* __restrict__ ow,
    const float* __restrict__ featg, const float* __restrict__ aw1,
    const float* __restrict__ ab1, const float* __restrict__ aw2,
    const float* __restrict__ ab2, float* __restrict__ es,
    float* __restrict__ absb)
{
  __shared__ float sm[8448 + 8704 + 1088 + 512];
  float* yl  = sm;               // [64][132]
  float* wo  = sm + 8448;        // [128][68], wo[k*68+f] = ow[f*128+k]
  float* aw  = wo + 8704;        // [16][68]
  float* prt = aw + 1088;        // [8][64]
  const int tid = threadIdx.x;
  const int base = blockIdx.x * 64;
  for (int idx = tid; idx < 64 * 128; idx += 512) {
    int r = idx >> 7, k = idx & 127;
    int n = base + r;
    yl[r * 132 + k] = (n < N_SEQ) ? y[n * 128 + k] : 0.f;
  }
  for (int idx = tid; idx < 64 * 128; idx += 512) {
    int f = idx >> 7, k = idx & 127;
    wo[k * 68 + f] = ow[idx];
  }
  for (int idx = tid; idx < 16 * 64; idx += 512) {
    int j = idx >> 6, f = idx & 63;
    aw[j * 68 + f] = aw1[idx];
  }
  __syncthreads();
  const int fg = tid & 15;
  const int rb = tid >> 4;       // rows rb, rb+32
  float acc[2][4];
  #pragma unroll
  for (int i = 0; i < 2; i++) {
    int n = base + rb + 32 * i;
    if (n < N_SEQ) {
      float4 fv = *(const float4*)&featg[n * 64 + fg * 4];
      acc[i][0]=fv.x; acc[i][1]=fv.y; acc[i][2]=fv.z; acc[i][3]=fv.w;
    } else { acc[i][0]=0; acc[i][1]=0; acc[i][2]=0; acc[i][3]=0; }
  }
  #pragma unroll 4
  for (int k = 0; k < 128; k += 4) {
    float4 y0 = *(const float4*)&yl[(rb +  0) * 132 + k];
    float4 y1 = *(const float4*)&yl[(rb + 32) * 132 + k];
    float4 w0 = *(const float4*)&wo[(k + 0) * 68 + fg * 4];
    float4 w1 = *(const float4*)&wo[(k + 1) * 68 + fg * 4];
    float4 w2 = *(const float4*)&wo[(k + 2) * 68 + fg * 4];
    float4 w3 = *(const float4*)&wo[(k + 3) * 68 + fg * 4];
    acc[0][0] += y0.x*w0.x + y0.y*w1.x + y0.z*w2.x + y0.w*w3.x;
    acc[0][1] += y0.x*w0.y + y0.y*w1.y + y0.z*w2.y + y0.w*w3.y;
    acc[0][2] += y0.x*w0.z + y0.y*w1.z + y0.z*w2.z + y0.w*w3.z;
    acc[0][3] += y0.x*w0.w + y0.y*w1.w + y0.z*w2.w + y0.w*w3.w;
    acc[1][0] += y1.x*w0.x + y1.y*w1.x + y1.z*w2.x + y1.w*w3.x;
    acc[1][1] += y1.x*w0.y + y1.y*w1.y + y1.z*w2.y + y1.w*w3.y;
    acc[1][2] += y1.x*w0.z + y1.y*w1.z + y1.z*w2.z + y1.w*w3.z;
    acc[1][3] += y1.x*w0.w + y1.y*w1.w + y1.z*w2.w + y1.w*w3.w;
  }
  __syncthreads();  // all yl reads done before aliasing as feat storage
  float* flds = sm;  // [64][68]
  #pragma unroll
  for (int i = 0; i < 2; i++) {
    int r = rb + 32 * i;
    float4 o = {acc[i][0], acc[i][1], acc[i][2], acc[i][3]};
    *(float4*)&flds[r * 68 + fg * 4] = o;
  }
  __syncthreads();
  const int r = tid & 63, jg = tid >> 6;   // jg 0..7
  float psum = 0.f;
  #pragma unroll
  for (int jj = 0; jj < 2; jj++) {
    int j = jg * 2 + jj;
    float d = ab1[j];
    #pragma unroll
    for (int k = 0; k < 64; k += 4) {
      float4 fv = *(const float4*)&flds[r * 68 + k];
      float4 wv = *(const float4*)&aw[j * 68 + k];
      d += DOT4(fv, wv);
    }
    psum += tanhf(d) * aw2[j];
  }
  prt[jg * 64 + r] = psum;
  __syncthreads();
  if (tid < 64) {
    int n = base + tid;
    float s = ab2[0];
    #pragma unroll
    for (int g = 0; g < 8; g++) s += prt[g * 64 + tid];
    float e = 0.f;
    if (n < N_SEQ) { e = __expf(s); es[n] = e; }
    #pragma unroll
    for (int off = 32; off > 0; off >>= 1) e += __shfl_down(e, off, 64);
    if (tid == 0) absb[blockIdx.x] = e;
  }
}

// K7a: S = sum of per-block exp sums; red[0] = 1/S
__global__ __launch_bounds__(512) void k7a_stats(
    const float* __restrict__ absb, float* __restrict__ red)
{
  __shared__ float sm[512];
  const int t = threadIdx.x;
  sm[t] = (t < NCH) ? absb[t] : 0.f;
  __syncthreads();
  for (int s = 256; s > 0; s >>= 1) { if (t < s) sm[t] += sm[t + s]; __syncthreads(); }
  if (t == 0) red[0] = 1.f / sm[0];
}

// K7b: write A_soft = es*inv and per-block partial M
__global__ __launch_bounds__(256) void k7b_weighted(
    const float* __restrict__ es, const float* __restrict__ featg,
    const float* __restrict__ red, float* __restrict__ out, float* __restrict__ Mp)
{
  __shared__ float prt[4 * 64];
  const int tid = threadIdx.x;
  const int base = blockIdx.x * 256;
  const float inv = red[0];
  const int f = tid & 63, g = tid >> 6;
  float acc = 0.f;
  for (int rr = g; rr < 256; rr += 4) {
    int n = base + rr;
    if (n < N_SEQ) acc += es[n] * inv * featg[n * 64 + f];
  }
  prt[g * 64 + f] = acc;
  int n = base + tid;
  if (n < N_SEQ) out[64 + n] = es[n] * inv;
  __syncthreads();
  if (tid < 64) Mp[blockIdx.x * 64 + tid] = prt[tid] + prt[64 + tid] + prt[128 + tid] + prt[192 + tid];
}

// K7c: M = sum of partials
__global__ __launch_bounds__(64) void k7c_reduceM(
    const float* __restrict__ Mp, float* __restrict__ out)
{
  const int f = threadIdx.x;
  float s = 0.f;
  for (int b = 0; b < NB7; b++) s += Mp[b * 64 + f];
  out[f] = s;
}

extern "C" void kernel_launch(void* const* d_in, const int* in_sizes, int n_in,
                              void* d_out, int out_size, void* d_ws, size_t ws_size,
                              hipStream_t stream)
{
  const float* xp   = (const float*)d_in[0];
  const float* W1   = (const float*)d_in[1];
  const float* b1   = (const float*)d_in[2];
  const float* ipw  = (const float*)d_in[3];
  const float* cw   = (const float*)d_in[4];
  const float* cb   = (const float*)d_in[5];
  const float* xpw  = (const float*)d_in[6];
  const float* dtw  = (const float*)d_in[7];
  const float* dtb  = (const float*)d_in[8];
  const float* Alog = (const float*)d_in[9];
  const float* Dsk  = (const float*)d_in[10];
  const float* ow   = (const float*)d_in[11];
  const float* aw1  = (const float*)d_in[12];
  const float* ab1  = (const float*)d_in[13];
  const float* aw2  = (const float*)d_in[14];
  const float* ab2  = (const float*)d_in[15];

  float* ws = (float*)d_ws;
  float* feature = ws;                       // 1,280,000
  float* xz_x = feature + 1280000;           // 2,560,000 (y alias after k3)
  float* zs   = xz_x + 2560000;              // 2,560,000
  float* xc   = zs + 2560000;                // 2,560,000
  float* dt   = xc + 2560000;                // 2,560,000
  float* Bm   = dt + 2560000;                // 320,000
  float* Cm   = Bm + 320000;                 // 320,000
  float* Pb   = Cm + 320000;                 // 641,024 (hi alias after k5)
  float* he   = Pb + 641024;                 // 641,024
  float* esb  = he + 641024;                 // 20,000 (exp of logits)
  float* absb = esb + 20000;                 // 320 (per-block exp sums)
  float* red  = absb + 320;                  // 16
  float* Mp   = red + 16;                    // 5,056
  ushort* whi = (ushort*)(Mp + 5056);        // 65,536 ushorts
  ushort* wlo = whi + 65536;                 // 65,536 ushorts
  float* part = (float*)(wlo + 65536);       // 4 x 1,280,000 (dedicated; no alias)
  float* hi   = Pb;
  float* yv   = xz_x;
  float* out  = (float*)d_out;

  k0_convW<<<256, 256, 0, stream>>>(W1, whi, wlo);
  k1m_mfma<<<dim3(313, 4), 256, 0, stream>>>(xp, whi, wlo, part);
  k2f_inproj<<<313, 256, 0, stream>>>(part, b1, ipw, feature, xz_x, zs);
  k3_conv_proj<<<417, 512, 0, stream>>>(xz_x, cw, cb, xpw, dtw, dtb, xc, dt, Bm, Cm);
  k4_scanA<<<NCH, 512, 0, stream>>>(dt, xc, Bm, Alog, Pb, he);
  k5_carry<<<8, 256, 0, stream>>>(Pb, he, hi);
  k6_scanC<<<NCH, 512, 0, stream>>>(dt, xc, Bm, Cm, zs, Alog, Dsk, hi, yv);
  k6b_out_attn<<<313, 512, 0, stream>>>(yv, ow, feature, aw1, ab1, aw2, ab2, esb, absb);
  k7a_stats<<<1, 512, 0, stream>>>(absb, red);
  k7b_weighted<<<NB7, 256, 0, stream>>>(esb, feature, red, out, Mp);
  k7c_reduceM<<<1, 64, 0, stream>>>(Mp, out);
}

// Round 9
// 225.446 us; speedup vs baseline: 2.0156x; 2.0156x over previous
//
#include <hip/hip_runtime.h>
#include <math.h>

#define N_SEQ 20000
#define LCH 64
#define NCH 313   // ceil(20000/64)
#define NB7 79    // ceil(20000/256)
#define PF 16     // k5 prefetch depth

#define DOT4(a,b) ((a).x*(b).x + (a).y*(b).y + (a).z*(b).z + (a).w*(b).w)

typedef __attribute__((ext_vector_type(8))) short short8b;   // 8 bf16 (4 VGPR)
typedef __attribute__((ext_vector_type(4))) float f32x4;

__device__ __forceinline__ float siluf(float v) { return v / (1.f + __expf(-v)); }

__device__ __forceinline__ ushort bf16rne(float f) {
  uint u = __float_as_uint(f);
  return (ushort)((u + 0x7fffu + ((u >> 16) & 1u)) >> 16);
}
__device__ __forceinline__ float bf2f(ushort h) { return __uint_as_float(((uint)h) << 16); }

__device__ __forceinline__ void cvt8(const float4 v0, const float4 v1,
                                     short8b& hi, short8b& lo) {
  float a[8] = {v0.x, v0.y, v0.z, v0.w, v1.x, v1.y, v1.z, v1.w};
  #pragma unroll
  for (int j = 0; j < 8; j++) {
    ushort h = bf16rne(a[j]);
    hi[j] = (short)h;
    lo[j] = (short)bf16rne(a[j] - bf2f(h));
  }
}

// K0: one-time W1 f32 -> bf16 hi/lo planes (64x1024)
__global__ __launch_bounds__(256) void k0_convW(
    const float* __restrict__ W1, ushort* __restrict__ whi, ushort* __restrict__ wlo)
{
  int i = blockIdx.x * 256 + threadIdx.x;   // 65536 elems
  float v = W1[i];
  ushort h = bf16rne(v);
  whi[i] = h;
  wlo[i] = bf16rne(v - bf2f(h));
}

// K1m: partial = x_path[rb:rb+64] @ W1.T over K slice blockIdx.y*128.
// No LDS, no barriers. K-split 8 for TLP; unroll 1 to cap VGPR.
__global__ __launch_bounds__(256) void k1m_mfma(
    const float* __restrict__ xp, const ushort* __restrict__ whi,
    const ushort* __restrict__ wlo, float* __restrict__ part)
{
  const int tid = threadIdx.x;
  const int wv = tid >> 6, lane = tid & 63;
  const int i16 = lane & 15, kb = lane >> 4;
  const int rb = blockIdx.x * 64;
  const int row = rb + wv * 16 + i16;
  const int kbase = blockIdx.y * 128;
  const bool valid = row < N_SEQ;
  const float* asrc = xp + (size_t)row * 1024 + kbase + kb * 8;
  const ushort* bh0 = whi + kbase + kb * 8;
  const ushort* bl0 = wlo + kbase + kb * 8;

  f32x4 acc[4];
  #pragma unroll
  for (int nt = 0; nt < 4; nt++) acc[nt] = (f32x4){0.f, 0.f, 0.f, 0.f};

  #pragma unroll 1
  for (int ks = 0; ks < 4; ks++) {
    short8b ahf, alf;
    if (valid) {
      float4 v0 = *(const float4*)&asrc[ks * 32 + 0];
      float4 v1 = *(const float4*)&asrc[ks * 32 + 4];
      cvt8(v0, v1, ahf, alf);
    } else {
      #pragma unroll
      for (int j = 0; j < 8; j++) { ahf[j] = 0; alf[j] = 0; }
    }
    #pragma unroll
    for (int nt = 0; nt < 4; nt++) {
      const size_t boff = (size_t)(nt * 16 + i16) * 1024 + ks * 32;
      short8b bhf = *(const short8b*)&bh0[boff];
      short8b blf = *(const short8b*)&bl0[boff];
      acc[nt] = __builtin_amdgcn_mfma_f32_16x16x32_bf16(ahf, bhf, acc[nt], 0, 0, 0);
      acc[nt] = __builtin_amdgcn_mfma_f32_16x16x32_bf16(ahf, blf, acc[nt], 0, 0, 0);
      acc[nt] = __builtin_amdgcn_mfma_f32_16x16x32_bf16(alf, bhf, acc[nt], 0, 0, 0);
    }
  }
  // D: row (in wave M-tile) = kb*4 + r, col = nt*16 + i16
  float* pb = part + blockIdx.y * 1280000;
  #pragma unroll
  for (int nt = 0; nt < 4; nt++)
    #pragma unroll
    for (int r = 0; r < 4; r++) {
      int n = rb + wv * 16 + kb * 4 + r;
      if (n < N_SEQ) pb[n * 64 + nt * 16 + i16] = acc[nt][r];
    }
}

// K1r: feature = relu(sum of 8 partials + b1)
__global__ __launch_bounds__(256) void k1r_reduce(
    const float* __restrict__ part, const float* __restrict__ b1,
    float* __restrict__ feat)
{
  int i4 = blockIdx.x * 256 + threadIdx.x;   // float4 index, 320000 total
  if (i4 >= 320000) return;
  float4 s = *(const float4*)&part[i4 * 4];
  #pragma unroll
  for (int p = 1; p < 8; p++) {
    float4 v = *(const float4*)&part[p * 1280000 + i4 * 4];
    s.x += v.x; s.y += v.y; s.z += v.z; s.w += v.w;
  }
  float4 bv = *(const float4*)&b1[(i4 & 15) * 4];
  float4 o;
  o.x = fmaxf(s.x + bv.x, 0.f);
  o.y = fmaxf(s.y + bv.y, 0.f);
  o.z = fmaxf(s.z + bv.z, 0.f);
  o.w = fmaxf(s.w + bv.w, 0.f);
  *(float4*)&feat[i4 * 4] = o;
}

// K2: xz = feature @ in_proj_w.T ; split -> xz_x (raw), zs = silu(z)
// grid (313, 4): 64-row x 64-col tiles, K=64 staged in 32-chunks (proven VGPR-64 form)
__global__ __launch_bounds__(256) void k2_inproj(
    const float* __restrict__ featg, const float* __restrict__ ipw,
    float* __restrict__ xz_x, float* __restrict__ zs)
{
  __shared__ float fs[32][68];   // [k][row]
  __shared__ float wl[32][68];   // [k][col]
  const int tid = threadIdx.x;
  const int rb = blockIdx.x * 64;
  const int cb = blockIdx.y * 64;
  const int tr = tid >> 4, tc = tid & 15;
  float acc[4][4] = {};
  for (int k0 = 0; k0 < 64; k0 += 32) {
    #pragma unroll
    for (int i = 0; i < 8; i++) {
      int idx = tid + i * 256;
      int r = idx >> 5, k = idx & 31;
      int n = rb + r;
      fs[k][r] = (n < N_SEQ) ? featg[n * 64 + k0 + k] : 0.f;
      wl[k][r] = ipw[(cb + r) * 64 + k0 + k];
    }
    __syncthreads();
    #pragma unroll
    for (int k = 0; k < 32; k++) {
      float4 xv = *(const float4*)&fs[k][tr * 4];
      float4 wv = *(const float4*)&wl[k][tc * 4];
      acc[0][0] += xv.x*wv.x; acc[0][1] += xv.x*wv.y; acc[0][2] += xv.x*wv.z; acc[0][3] += xv.x*wv.w;
      acc[1][0] += xv.y*wv.x; acc[1][1] += xv.y*wv.y; acc[1][2] += xv.y*wv.z; acc[1][3] += xv.y*wv.w;
      acc[2][0] += xv.z*wv.x; acc[2][1] += xv.z*wv.y; acc[2][2] += xv.z*wv.z; acc[2][3] += xv.z*wv.w;
      acc[3][0] += xv.w*wv.x; acc[3][1] += xv.w*wv.y; acc[3][2] += xv.w*wv.z; acc[3][3] += xv.w*wv.w;
    }
    __syncthreads();
  }
  const int c0 = cb + tc * 4;
  #pragma unroll
  for (int i = 0; i < 4; i++) {
    int n = rb + tr * 4 + i;
    if (n < N_SEQ) {
      if (cb < 128) {
        float4 o = {acc[i][0], acc[i][1], acc[i][2], acc[i][3]};
        *(float4*)&xz_x[n * 128 + c0] = o;
      } else {
        float4 o = {siluf(acc[i][0]), siluf(acc[i][1]), siluf(acc[i][2]), siluf(acc[i][3])};
        *(float4*)&zs[n * 128 + c0 - 128] = o;
      }
    }
  }
}

// K3: causal depthwise conv + silu -> xc ; x_dbl = xc @ x_proj_w.T -> dt_raw,B,C ;
//     dt = softplus(dt_raw @ dt_proj_w.T + dt_proj_b)   [512 threads]
__global__ __launch_bounds__(512) void k3_conv_proj(
    const float* __restrict__ xz_x, const float* __restrict__ cw,
    const float* __restrict__ cb, const float* __restrict__ xpw,
    const float* __restrict__ dtw, const float* __restrict__ dtb,
    float* __restrict__ xc, float* __restrict__ dt,
    float* __restrict__ Bm, float* __restrict__ Cm)
{
  __shared__ float xzl[51 * 128];
  __shared__ float xcl[48 * 128];
  __shared__ float xwl[36 * 132];
  __shared__ float dtrl[48 * 4];
  const int tid = threadIdx.x;
  const int r0 = blockIdx.x * 48;
  for (int idx = tid; idx < 51 * 128; idx += 512) {
    int rg = r0 - 3 + (idx >> 7);
    int c = idx & 127;
    xzl[idx] = (rg >= 0 && rg < N_SEQ) ? xz_x[rg * 128 + c] : 0.f;
  }
  for (int idx = tid; idx < 36 * 128; idx += 512) {
    int j = idx >> 7, c = idx & 127;
    xwl[j * 132 + c] = xpw[idx];
  }
  __syncthreads();
  const int c = tid & 127;
  const int rbase = tid >> 7;  // 0..3
  const float4 cw4 = *(const float4*)&cw[c * 4];
  const float cbv = cb[c];
  #pragma unroll
  for (int i = 0; i < 12; i++) {
    int rl = rbase + 4 * i;
    float v = cw4.x * xzl[(rl+0)*128 + c] + cw4.y * xzl[(rl+1)*128 + c]
            + cw4.z * xzl[(rl+2)*128 + c] + cw4.w * xzl[(rl+3)*128 + c] + cbv;
    v = siluf(v);
    xcl[rl * 128 + c] = v;
    int n = r0 + rl;
    if (n < N_SEQ) xc[n * 128 + c] = v;
  }
  __syncthreads();
  for (int idx = tid; idx < 48 * 36; idx += 512) {
    int r = idx / 36, j = idx - r * 36;
    float s = 0.f;
    #pragma unroll
    for (int k = 0; k < 128; k += 4) {
      float4 a = *(const float4*)&xcl[r * 128 + k];
      float4 b = *(const float4*)&xwl[j * 132 + k];
      s += DOT4(a, b);
    }
    int n = r0 + r;
    if (j < 4) dtrl[r * 4 + j] = s;
    else if (n < N_SEQ) {
      if (j < 20) Bm[n * 16 + (j - 4)] = s;
      else        Cm[n * 16 + (j - 20)] = s;
    }
  }
  __syncthreads();
  const float4 dw4 = *(const float4*)&dtw[c * 4];
  const float dbv = dtb[c];
  #pragma unroll
  for (int i = 0; i < 12; i++) {
    int rl = rbase + 4 * i;
    int n = r0 + rl;
    if (n < N_SEQ) {
      float4 dr = *(const float4*)&dtrl[rl * 4];
      float v = DOT4(dr, dw4) + dbv;
      dt[n * 128 + c] = (v > 20.f) ? v : log1pf(__expf(v));
    }
  }
}

// K4 (phase A): per-chunk P and local scan end, LDS chunk-staged (16 rows/chunk, dbuf)
__global__ __launch_bounds__(512) void k4_scanA(
    const float* __restrict__ dt, const float* __restrict__ xc,
    const float* __restrict__ Bm, const float* __restrict__ Alog,
    float* __restrict__ Pb, float* __restrict__ he)
{
  __shared__ float sdt[2][2048];
  __shared__ float sxc[2][2048];
  __shared__ float sB[2][256];
  const int t = threadIdx.x;
  const int chunk = blockIdx.x;
  const int n0 = chunk * LCH;
  const int srow = t >> 5, scol = (t & 31) * 4;
  const int c = t >> 2, sq = t & 3;
  float4 al = *(const float4*)&Alog[t * 4];
  const float A0 = -__expf(al.x), A1 = -__expf(al.y), A2 = -__expf(al.z), A3 = -__expf(al.w);
  float h0=0,h1=0,h2=0,h3=0;
  float p0=1,p1=1,p2=1,p3=1;

  auto stage = [&](int cb, int buf) {
    int n = n0 + cb * 16 + srow;
    float4 vd = {0,0,0,0}, vx = {0,0,0,0};
    if (n < N_SEQ) {
      vd = *(const float4*)&dt[n * 128 + scol];
      vx = *(const float4*)&xc[n * 128 + scol];
    }
    *(float4*)&sdt[buf][srow * 128 + scol] = vd;
    *(float4*)&sxc[buf][srow * 128 + scol] = vx;
    if (t < 64) {
      int br = t >> 2, bq = (t & 3) * 4;
      int nb = n0 + cb * 16 + br;
      float4 vb = {0,0,0,0};
      if (nb < N_SEQ) vb = *(const float4*)&Bm[nb * 16 + bq];
      *(float4*)&sB[buf][br * 16 + bq] = vb;
    }
  };

  stage(0, 0);
  __syncthreads();
  int cur = 0;
  for (int cb = 0; cb < 4; cb++) {
    if (cb + 1 < 4) stage(cb + 1, cur ^ 1);
    #pragma unroll
    for (int rl = 0; rl < 16; rl++) {
      float dtv = sdt[cur][rl * 128 + c];
      float xv  = sxc[cur][rl * 128 + c];
      float4 Bv = *(const float4*)&sB[cur][rl * 16 + sq * 4];
      float bs = dtv * xv;
      float e0 = __expf(dtv*A0), e1 = __expf(dtv*A1), e2 = __expf(dtv*A2), e3 = __expf(dtv*A3);
      h0 = e0*h0 + bs*Bv.x; h1 = e1*h1 + bs*Bv.y; h2 = e2*h2 + bs*Bv.z; h3 = e3*h3 + bs*Bv.w;
      p0 *= e0; p1 *= e1; p2 *= e2; p3 *= e3;
    }
    __syncthreads();
    cur ^= 1;
  }
  const int base = chunk * 2048 + t * 4;
  float4 P4 = {p0,p1,p2,p3}; *(float4*)&Pb[base] = P4;
  float4 H4 = {h0,h1,h2,h3}; *(float4*)&he[base] = H4;
}

// K5 (phase B): sequential carry over chunks, 8 blocks x 256 threads, 16-deep prefetch.
// NOTE: hi aliases Pb — no __restrict__ here so program-order load/store is kept.
__global__ __launch_bounds__(256) void k5_carry(
    const float* Pb, const float* he, float* hi)
{
  const int q = blockIdx.x * 256 + threadIdx.x;   // chain id, 0..2047
  float pr[PF], er[PF];
  #pragma unroll
  for (int j = 0; j < PF; j++) {
    pr[j] = Pb[j * 2048 + q];
    er[j] = he[j * 2048 + q];
  }
  float h = 0.f;
  for (int k = 0; k < NCH; k += PF) {
    #pragma unroll
    for (int j = 0; j < PF; j++) {
      int kk = k + j;
      if (kk < NCH) {
        hi[kk * 2048 + q] = h;
        h = fmaf(pr[j], h, er[j]);
        int kn = kk + PF;
        if (kn < NCH) {
          pr[j] = Pb[kn * 2048 + q];
          er[j] = he[kn * 2048 + q];
        }
      }
    }
  }
}

// K6 (phase C): replay scan with carries, fused ys*C + D-skip + z-gate -> y
__global__ __launch_bounds__(512) void k6_scanC(
    const float* __restrict__ dt, const float* __restrict__ xc,
    const float* __restrict__ Bm, const float* __restrict__ Cm,
    const float* __restrict__ zs, const float* __restrict__ Alog,
    const float* __restrict__ Dsk, const float* __restrict__ hi,
    float* __restrict__ y)
{
  __shared__ float sdt[2][2048];
  __shared__ float sxc[2][2048];
  __shared__ float szs[2][2048];
  __shared__ float sBC[2][512];
  const int t = threadIdx.x;
  const int chunk = blockIdx.x;
  const int n0 = chunk * LCH;
  const int srow = t >> 5, scol = (t & 31) * 4;
  const int c = t >> 2, sq = t & 3;
  float4 al = *(const float4*)&Alog[t * 4];
  const float A0 = -__expf(al.x), A1 = -__expf(al.y), A2 = -__expf(al.z), A3 = -__expf(al.w);
  float4 h4 = *(const float4*)&hi[chunk * 2048 + t * 4];
  float h0 = h4.x, h1 = h4.y, h2 = h4.z, h3 = h4.w;
  const float Dc = Dsk[c];

  auto stage = [&](int cb, int buf) {
    int n = n0 + cb * 16 + srow;
    float4 vd = {0,0,0,0}, vx = {0,0,0,0}, vz = {0,0,0,0};
    if (n < N_SEQ) {
      vd = *(const float4*)&dt[n * 128 + scol];
      vx = *(const float4*)&xc[n * 128 + scol];
      vz = *(const float4*)&zs[n * 128 + scol];
    }
    *(float4*)&sdt[buf][srow * 128 + scol] = vd;
    *(float4*)&sxc[buf][srow * 128 + scol] = vx;
    *(float4*)&szs[buf][srow * 128 + scol] = vz;
    if (t < 128) {
      int sel = t >> 6;           // 0: B, 1: C
      int u = t & 63;
      int br = u >> 2, bq = (u & 3) * 4;
      int nb = n0 + cb * 16 + br;
      float4 v = {0,0,0,0};
      if (nb < N_SEQ) v = sel ? *(const float4*)&Cm[nb * 16 + bq]
                              : *(const float4*)&Bm[nb * 16 + bq];
      *(float4*)&sBC[buf][sel * 256 + br * 16 + bq] = v;
    }
  };

  stage(0, 0);
  __syncthreads();
  int cur = 0;
  for (int cb = 0; cb < 4; cb++) {
    if (cb + 1 < 4) stage(cb + 1, cur ^ 1);
    #pragma unroll
    for (int rl = 0; rl < 16; rl++) {
      float dtv = sdt[cur][rl * 128 + c];
      float xv  = sxc[cur][rl * 128 + c];
      float zv  = szs[cur][rl * 128 + c];
      float4 Bv = *(const float4*)&sBC[cur][rl * 16 + sq * 4];
      float4 Cv = *(const float4*)&sBC[cur][256 + rl * 16 + sq * 4];
      float bs = dtv * xv;
      float e0 = __expf(dtv*A0), e1 = __expf(dtv*A1), e2 = __expf(dtv*A2), e3 = __expf(dtv*A3);
      h0 = e0*h0 + bs*Bv.x; h1 = e1*h1 + bs*Bv.y; h2 = e2*h2 + bs*Bv.z; h3 = e3*h3 + bs*Bv.w;
      float part = h0*Cv.x + h1*Cv.y + h2*Cv.z + h3*Cv.w;
      part += __shfl_xor(part, 1, 64);
      part += __shfl_xor(part, 2, 64);
      int n = n0 + cb * 16 + rl;
      if (sq == 0 && n < N_SEQ) y[n * 128 + c] = (part + Dc * xv) * zv;
    }
    __syncthreads();
    cur ^= 1;
  }
}

// K6b: feat = y @ out_proj_w.T + feature ; es[n]=exp(logit), per-block sums   [512 threads]
__global__ __launch_bounds__(512) void k6b_out_attn(
    const float* __restrict__ y, const float* __restrict__ ow,
    const float* __restrict__ featg, const float* __restrict__ aw1,
    const float* __restrict__ ab1, const float* __restrict__ aw2,
    const float* __restrict__ ab2, float* __restrict__ es,
    float* __restrict__ absb)
{
  __shared__ float sm[8448 + 8704 + 1088 + 512];
  float* yl  = sm;               // [64][132]
  float* wo  = sm + 8448;        // [128][68], wo[k*68+f] = ow[f*128+k]
  float* aw  = wo + 8704;        // [16][68]
  float* prt = aw + 1088;        // [8][64]
  const int tid = threadIdx.x;
  const int base = blockIdx.x * 64;
  for (int idx = tid; idx < 64 * 128; idx += 512) {
    int r = idx >> 7, k = idx & 127;
    int n = base + r;
    yl[r * 132 + k] = (n < N_SEQ) ? y[n * 128 + k] : 0.f;
  }
  for (int idx = tid; idx < 64 * 128; idx += 512) {
    int f = idx >> 7, k = idx & 127;
    wo[k * 68 + f] = ow[idx];
  }
  for (int idx = tid; idx < 16 * 64; idx += 512) {
    int j = idx >> 6, f = idx & 63;
    aw[j * 68 + f] = aw1[idx];
  }
  __syncthreads();
  const int fg = tid & 15;
  const int rb = tid >> 4;       // rows rb, rb+32
  float acc[2][4];
  #pragma unroll
  for (int i = 0; i < 2; i++) {
    int n = base + rb + 32 * i;
    if (n < N_SEQ) {
      float4 fv = *(const float4*)&featg[n * 64 + fg * 4];
      acc[i][0]=fv.x; acc[i][1]=fv.y; acc[i][2]=fv.z; acc[i][3]=fv.w;
    } else { acc[i][0]=0; acc[i][1]=0; acc[i][2]=0; acc[i][3]=0; }
  }
  #pragma unroll 4
  for (int k = 0; k < 128; k += 4) {
    float4 y0 = *(const float4*)&yl[(rb +  0) * 132 + k];
    float4 y1 = *(const float4*)&yl[(rb + 32) * 132 + k];
    float4 w0 = *(const float4*)&wo[(k + 0) * 68 + fg * 4];
    float4 w1 = *(const float4*)&wo[(k + 1) * 68 + fg * 4];
    float4 w2 = *(const float4*)&wo[(k + 2) * 68 + fg * 4];
    float4 w3 = *(const float4*)&wo[(k + 3) * 68 + fg * 4];
    acc[0][0] += y0.x*w0.x + y0.y*w1.x + y0.z*w2.x + y0.w*w3.x;
    acc[0][1] += y0.x*w0.y + y0.y*w1.y + y0.z*w2.y + y0.w*w3.y;
    acc[0][2] += y0.x*w0.z + y0.y*w1.z + y0.z*w2.z + y0.w*w3.z;
    acc[0][3] += y0.x*w0.w + y0.y*w1.w + y0.z*w2.w + y0.w*w3.w;
    acc[1][0] += y1.x*w0.x + y1.y*w1.x + y1.z*w2.x + y1.w*w3.x;
    acc[1][1] += y1.x*w0.y + y1.y*w1.y + y1.z*w2.y + y1.w*w3.y;
    acc[1][2] += y1.x*w0.z + y1.y*w1.z + y1.z*w2.z + y1.w*w3.z;
    acc[1][3] += y1.x*w0.w + y1.y*w1.w + y1.z*w2.w + y1.w*w3.w;
  }
  __syncthreads();  // all yl reads done before aliasing as feat storage
  float* flds = sm;  // [64][68]
  #pragma unroll
  for (int i = 0; i < 2; i++) {
    int r = rb + 32 * i;
    float4 o = {acc[i][0], acc[i][1], acc[i][2], acc[i][3]};
    *(float4*)&flds[r * 68 + fg * 4] = o;
  }
  __syncthreads();
  const int r = tid & 63, jg = tid >> 6;   // jg 0..7
  float psum = 0.f;
  #pragma unroll
  for (int jj = 0; jj < 2; jj++) {
    int j = jg * 2 + jj;
    float d = ab1[j];
    #pragma unroll
    for (int k = 0; k < 64; k += 4) {
      float4 fv = *(const float4*)&flds[r * 68 + k];
      float4 wv = *(const float4*)&aw[j * 68 + k];
      d += DOT4(fv, wv);
    }
    psum += tanhf(d) * aw2[j];
  }
  prt[jg * 64 + r] = psum;
  __syncthreads();
  if (tid < 64) {
    int n = base + tid;
    float s = ab2[0];
    #pragma unroll
    for (int g = 0; g < 8; g++) s += prt[g * 64 + tid];
    float e = 0.f;
    if (n < N_SEQ) { e = __expf(s); es[n] = e; }
    #pragma unroll
    for (int off = 32; off > 0; off >>= 1) e += __shfl_down(e, off, 64);
    if (tid == 0) absb[blockIdx.x] = e;
  }
}

// K7a: S = sum of per-block exp sums; red[0] = 1/S
__global__ __launch_bounds__(512) void k7a_stats(
    const float* __restrict__ absb, float* __restrict__ red)
{
  __shared__ float sm[512];
  const int t = threadIdx.x;
  sm[t] = (t < NCH) ? absb[t] : 0.f;
  __syncthreads();
  for (int s = 256; s > 0; s >>= 1) { if (t < s) sm[t] += sm[t + s]; __syncthreads(); }
  if (t == 0) red[0] = 1.f / sm[0];
}

// K7b: write A_soft = es*inv and per-block partial M
__global__ __launch_bounds__(256) void k7b_weighted(
    const float* __restrict__ es, const float* __restrict__ featg,
    const float* __restrict__ red, float* __restrict__ out, float* __restrict__ Mp)
{
  __shared__ float prt[4 * 64];
  const int tid = threadIdx.x;
  const int base = blockIdx.x * 256;
  const float inv = red[0];
  const int f = tid & 63, g = tid >> 6;
  float acc = 0.f;
  for (int rr = g; rr < 256; rr += 4) {
    int n = base + rr;
    if (n < N_SEQ) acc += es[n] * inv * featg[n * 64 + f];
  }
  prt[g * 64 + f] = acc;
  int n = base + tid;
  if (n < N_SEQ) out[64 + n] = es[n] * inv;
  __syncthreads();
  if (tid < 64) Mp[blockIdx.x * 64 + tid] = prt[tid] + prt[64 + tid] + prt[128 + tid] + prt[192 + tid];
}

// K7c: M = sum of partials
__global__ __launch_bounds__(64) void k7c_reduceM(
    const float* __restrict__ Mp, float* __restrict__ out)
{
  const int f = threadIdx.x;
  float s = 0.f;
  for (int b = 0; b < NB7; b++) s += Mp[b * 64 + f];
  out[f] = s;
}

extern "C" void kernel_launch(void* const* d_in, const int* in_sizes, int n_in,
                              void* d_out, int out_size, void* d_ws, size_t ws_size,
                              hipStream_t stream)
{
  const float* xp   = (const float*)d_in[0];
  const float* W1   = (const float*)d_in[1];
  const float* b1   = (const float*)d_in[2];
  const float* ipw  = (const float*)d_in[3];
  const float* cw   = (const float*)d_in[4];
  const float* cb   = (const float*)d_in[5];
  const float* xpw  = (const float*)d_in[6];
  const float* dtw  = (const float*)d_in[7];
  const float* dtb  = (const float*)d_in[8];
  const float* Alog = (const float*)d_in[9];
  const float* Dsk  = (const float*)d_in[10];
  const float* ow   = (const float*)d_in[11];
  const float* aw1  = (const float*)d_in[12];
  const float* ab1  = (const float*)d_in[13];
  const float* aw2  = (const float*)d_in[14];
  const float* ab2  = (const float*)d_in[15];

  float* ws = (float*)d_ws;
  float* feature = ws;                       // 1,280,000
  float* xz_x = feature + 1280000;           // 2,560,000 (y alias after k3)
  float* zs   = xz_x + 2560000;              // 2,560,000
  float* xc   = zs + 2560000;                // 2,560,000
  float* dt   = xc + 2560000;                // 2,560,000
  float* Bm   = dt + 2560000;                // 320,000
  float* Cm   = Bm + 320000;                 // 320,000
  float* Pb   = Cm + 320000;                 // 641,024 (hi alias after k5)
  float* he   = Pb + 641024;                 // 641,024
  float* esb  = he + 641024;                 // 20,000 (exp of logits)
  float* absb = esb + 20000;                 // 320 (per-block exp sums)
  float* red  = absb + 320;                  // 16
  float* Mp   = red + 16;                    // 5,056
  ushort* whi = (ushort*)(Mp + 5056);        // 65,536 ushorts
  ushort* wlo = whi + 65536;                 // 65,536 ushorts
  float* part = (float*)(wlo + 65536);       // 8 x 1,280,000 (dedicated)
  float* hi   = Pb;
  float* yv   = xz_x;
  float* out  = (float*)d_out;

  k0_convW<<<256, 256, 0, stream>>>(W1, whi, wlo);
  k1m_mfma<<<dim3(313, 8), 256, 0, stream>>>(xp, whi, wlo, part);
  k1r_reduce<<<1250, 256, 0, stream>>>(part, b1, feature);
  k2_inproj<<<dim3(313, 4), 256, 0, stream>>>(feature, ipw, xz_x, zs);
  k3_conv_proj<<<417, 512, 0, stream>>>(xz_x, cw, cb, xpw, dtw, dtb, xc, dt, Bm, Cm);
  k4_scanA<<<NCH, 512, 0, stream>>>(dt, xc, Bm, Alog, Pb, he);
  k5_carry<<<8, 256, 0, stream>>>(Pb, he, hi);
  k6_scanC<<<NCH, 512, 0, stream>>>(dt, xc, Bm, Cm, zs, Alog, Dsk, hi, yv);
  k6b_out_attn<<<313, 512, 0, stream>>>(yv, ow, feature, aw1, ab1, aw2, ab2, esb, absb);
  k7a_stats<<<1, 512, 0, stream>>>(absb, red);
  k7b_weighted<<<NB7, 256, 0, stream>>>(esb, feature, red, out, Mp);
  k7c_reduceM<<<1, 64, 0, stream>>>(Mp, out);
}

// Round 10
// 192.858 us; speedup vs baseline: 2.3561x; 1.1690x over previous
//
#include <hip/hip_runtime.h>
#include <math.h>

#define N_SEQ 20000
#define LCH 64
#define NCH 313   // ceil(20000/64)
#define NB7 79    // ceil(20000/256)
#define PF 16     // k5 prefetch depth

#define DOT4(a,b) ((a).x*(b).x + (a).y*(b).y + (a).z*(b).z + (a).w*(b).w)

typedef __attribute__((ext_vector_type(8))) short short8b;   // 8 bf16 (4 VGPR)
typedef __attribute__((ext_vector_type(4))) float f32x4;

__device__ __forceinline__ float siluf(float v) { return v / (1.f + __expf(-v)); }

__device__ __forceinline__ ushort bf16rne(float f) {
  uint u = __float_as_uint(f);
  return (ushort)((u + 0x7fffu + ((u >> 16) & 1u)) >> 16);
}
__device__ __forceinline__ float bf2f(ushort h) { return __uint_as_float(((uint)h) << 16); }

// K0: one-time W1 f32 -> bf16 hi/lo planes (64x1024)
__global__ __launch_bounds__(256) void k0_convW(
    const float* __restrict__ W1, ushort* __restrict__ whi, ushort* __restrict__ wlo)
{
  int i = blockIdx.x * 256 + threadIdx.x;   // 65536 elems
  float v = W1[i];
  ushort h = bf16rne(v);
  whi[i] = h;
  wlo[i] = bf16rne(v - bf2f(h));
}

// K1m: partial = x_path[rb:rb+64] @ W1.T over K slice blockIdx.y*512 (bf16-split MFMA)
// 64-row tile, K=32 per stage, LDS stride 40 ushorts; B loaded preconverted.
// (round-7 form: LDS-staged = coalesced; the no-LDS variant was 16-way scattered)
__global__ __launch_bounds__(256) void k1m_mfma(
    const float* __restrict__ xp, const ushort* __restrict__ whi,
    const ushort* __restrict__ wlo, float* __restrict__ part)
{
  __shared__ ushort a_hi[64 * 40];
  __shared__ ushort a_lo[64 * 40];
  __shared__ ushort b_hi[64 * 40];
  __shared__ ushort b_lo[64 * 40];
  const int tid = threadIdx.x;
  const int rb = blockIdx.x * 64;
  const int kbase = blockIdx.y * 512;
  const int wv = tid >> 6, lane = tid & 63;
  const int i16 = lane & 15, kb = lane >> 4;
  const int srow = tid >> 2;           // 0..63
  const int skq = (tid & 3) * 8;       // k offset within 32
  f32x4 acc[4];
  #pragma unroll
  for (int nt = 0; nt < 4; nt++) acc[nt] = (f32x4){0.f, 0.f, 0.f, 0.f};

  for (int ks = 0; ks < 16; ks++) {
    const int k0 = kbase + ks * 32;
    // stage A (64 rows x 32 k) with f32->bf16 split
    {
      const int n = rb + srow;
      ushort* ah = &a_hi[srow * 40 + skq];
      ushort* al = &a_lo[srow * 40 + skq];
      if (n < N_SEQ) {
        const float* src = xp + (size_t)n * 1024 + k0 + skq;
        #pragma unroll
        for (int q = 0; q < 2; q++) {
          float4 v = *(const float4*)&src[q * 4];
          ushort4 h, l;
          h.x = bf16rne(v.x); l.x = bf16rne(v.x - bf2f(h.x));
          h.y = bf16rne(v.y); l.y = bf16rne(v.y - bf2f(h.y));
          h.z = bf16rne(v.z); l.z = bf16rne(v.z - bf2f(h.z));
          h.w = bf16rne(v.w); l.w = bf16rne(v.w - bf2f(h.w));
          *(ushort4*)&ah[q * 4] = h;
          *(ushort4*)&al[q * 4] = l;
        }
      } else {
        ushort4 z = {0, 0, 0, 0};
        *(ushort4*)&ah[0] = z; *(ushort4*)&ah[4] = z;
        *(ushort4*)&al[0] = z; *(ushort4*)&al[4] = z;
      }
    }
    // stage B: straight copy of preconverted planes
    {
      const size_t off = (size_t)srow * 1024 + k0 + skq;
      *(uint4*)&b_hi[srow * 40 + skq] = *(const uint4*)&whi[off];
      *(uint4*)&b_lo[srow * 40 + skq] = *(const uint4*)&wlo[off];
    }
    __syncthreads();
    // MFMA: 3-term bf16 split
    {
      const int koff = kb * 8;
      short8b ahf = *(const short8b*)&a_hi[(wv * 16 + i16) * 40 + koff];
      short8b alf = *(const short8b*)&a_lo[(wv * 16 + i16) * 40 + koff];
      #pragma unroll
      for (int nt = 0; nt < 4; nt++) {
        short8b bhf = *(const short8b*)&b_hi[(nt * 16 + i16) * 40 + koff];
        short8b blf = *(const short8b*)&b_lo[(nt * 16 + i16) * 40 + koff];
        acc[nt] = __builtin_amdgcn_mfma_f32_16x16x32_bf16(ahf, bhf, acc[nt], 0, 0, 0);
        acc[nt] = __builtin_amdgcn_mfma_f32_16x16x32_bf16(ahf, blf, acc[nt], 0, 0, 0);
        acc[nt] = __builtin_amdgcn_mfma_f32_16x16x32_bf16(alf, bhf, acc[nt], 0, 0, 0);
      }
    }
    __syncthreads();
  }
  float* pb = part + blockIdx.y * 1280000;
  #pragma unroll
  for (int nt = 0; nt < 4; nt++)
    #pragma unroll
    for (int r = 0; r < 4; r++) {
      int n = rb + wv * 16 + kb * 4 + r;
      if (n < N_SEQ) pb[n * 64 + nt * 16 + i16] = acc[nt][r];
    }
}

// K1r: feature = relu(sum of 2 partials + b1)
__global__ __launch_bounds__(256) void k1r_reduce(
    const float* __restrict__ part, const float* __restrict__ b1,
    float* __restrict__ feat)
{
  int i4 = blockIdx.x * 256 + threadIdx.x;   // float4 index, 320000 total
  if (i4 >= 320000) return;
  float4 a = *(const float4*)&part[i4 * 4];
  float4 b = *(const float4*)&part[1280000 + i4 * 4];
  float4 bv = *(const float4*)&b1[(i4 & 15) * 4];
  float4 o;
  o.x = fmaxf(a.x + b.x + bv.x, 0.f);
  o.y = fmaxf(a.y + b.y + bv.y, 0.f);
  o.z = fmaxf(a.z + b.z + bv.z, 0.f);
  o.w = fmaxf(a.w + b.w + bv.w, 0.f);
  *(float4*)&feat[i4 * 4] = o;
}

// K2: xz = feature @ in_proj_w.T ; split -> xz_x (raw), zs = silu(z)
// grid (313, 4): 64-row x 64-col tiles, K=64 staged in 32-chunks (proven VGPR-64 form)
__global__ __launch_bounds__(256) void k2_inproj(
    const float* __restrict__ featg, const float* __restrict__ ipw,
    float* __restrict__ xz_x, float* __restrict__ zs)
{
  __shared__ float fs[32][68];   // [k][row]
  __shared__ float wl[32][68];   // [k][col]
  const int tid = threadIdx.x;
  const int rb = blockIdx.x * 64;
  const int cb = blockIdx.y * 64;
  const int tr = tid >> 4, tc = tid & 15;
  float acc[4][4] = {};
  for (int k0 = 0; k0 < 64; k0 += 32) {
    #pragma unroll
    for (int i = 0; i < 8; i++) {
      int idx = tid + i * 256;
      int r = idx >> 5, k = idx & 31;
      int n = rb + r;
      fs[k][r] = (n < N_SEQ) ? featg[n * 64 + k0 + k] : 0.f;
      wl[k][r] = ipw[(cb + r) * 64 + k0 + k];
    }
    __syncthreads();
    #pragma unroll
    for (int k = 0; k < 32; k++) {
      float4 xv = *(const float4*)&fs[k][tr * 4];
      float4 wv = *(const float4*)&wl[k][tc * 4];
      acc[0][0] += xv.x*wv.x; acc[0][1] += xv.x*wv.y; acc[0][2] += xv.x*wv.z; acc[0][3] += xv.x*wv.w;
      acc[1][0] += xv.y*wv.x; acc[1][1] += xv.y*wv.y; acc[1][2] += xv.y*wv.z; acc[1][3] += xv.y*wv.w;
      acc[2][0] += xv.z*wv.x; acc[2][1] += xv.z*wv.y; acc[2][2] += xv.z*wv.z; acc[2][3] += xv.z*wv.w;
      acc[3][0] += xv.w*wv.x; acc[3][1] += xv.w*wv.y; acc[3][2] += xv.w*wv.z; acc[3][3] += xv.w*wv.w;
    }
    __syncthreads();
  }
  const int c0 = cb + tc * 4;
  #pragma unroll
  for (int i = 0; i < 4; i++) {
    int n = rb + tr * 4 + i;
    if (n < N_SEQ) {
      if (cb < 128) {
        float4 o = {acc[i][0], acc[i][1], acc[i][2], acc[i][3]};
        *(float4*)&xz_x[n * 128 + c0] = o;
      } else {
        float4 o = {siluf(acc[i][0]), siluf(acc[i][1]), siluf(acc[i][2]), siluf(acc[i][3])};
        *(float4*)&zs[n * 128 + c0 - 128] = o;
      }
    }
  }
}

// K3: causal depthwise conv + silu -> xc ; x_dbl = xc @ x_proj_w.T -> dt_raw,B,C ;
//     dt = softplus(dt_raw @ dt_proj_w.T + dt_proj_b)   [512 threads]
__global__ __launch_bounds__(512) void k3_conv_proj(
    const float* __restrict__ xz_x, const float* __restrict__ cw,
    const float* __restrict__ cb, const float* __restrict__ xpw,
    const float* __restrict__ dtw, const float* __restrict__ dtb,
    float* __restrict__ xc, float* __restrict__ dt,
    float* __restrict__ Bm, float* __restrict__ Cm)
{
  __shared__ float xzl[51 * 128];
  __shared__ float xcl[48 * 128];
  __shared__ float xwl[36 * 132];
  __shared__ float dtrl[48 * 4];
  const int tid = threadIdx.x;
  const int r0 = blockIdx.x * 48;
  for (int idx = tid; idx < 51 * 128; idx += 512) {
    int rg = r0 - 3 + (idx >> 7);
    int c = idx & 127;
    xzl[idx] = (rg >= 0 && rg < N_SEQ) ? xz_x[rg * 128 + c] : 0.f;
  }
  for (int idx = tid; idx < 36 * 128; idx += 512) {
    int j = idx >> 7, c = idx & 127;
    xwl[j * 132 + c] = xpw[idx];
  }
  __syncthreads();
  const int c = tid & 127;
  const int rbase = tid >> 7;  // 0..3
  const float4 cw4 = *(const float4*)&cw[c * 4];
  const float cbv = cb[c];
  #pragma unroll
  for (int i = 0; i < 12; i++) {
    int rl = rbase + 4 * i;
    float v = cw4.x * xzl[(rl+0)*128 + c] + cw4.y * xzl[(rl+1)*128 + c]
            + cw4.z * xzl[(rl+2)*128 + c] + cw4.w * xzl[(rl+3)*128 + c] + cbv;
    v = siluf(v);
    xcl[rl * 128 + c] = v;
    int n = r0 + rl;
    if (n < N_SEQ) xc[n * 128 + c] = v;
  }
  __syncthreads();
  for (int idx = tid; idx < 48 * 36; idx += 512) {
    int r = idx / 36, j = idx - r * 36;
    float s = 0.f;
    #pragma unroll
    for (int k = 0; k < 128; k += 4) {
      float4 a = *(const float4*)&xcl[r * 128 + k];
      float4 b = *(const float4*)&xwl[j * 132 + k];
      s += DOT4(a, b);
    }
    int n = r0 + r;
    if (j < 4) dtrl[r * 4 + j] = s;
    else if (n < N_SEQ) {
      if (j < 20) Bm[n * 16 + (j - 4)] = s;
      else        Cm[n * 16 + (j - 20)] = s;
    }
  }
  __syncthreads();
  const float4 dw4 = *(const float4*)&dtw[c * 4];
  const float dbv = dtb[c];
  #pragma unroll
  for (int i = 0; i < 12; i++) {
    int rl = rbase + 4 * i;
    int n = r0 + rl;
    if (n < N_SEQ) {
      float4 dr = *(const float4*)&dtrl[rl * 4];
      float v = DOT4(dr, dw4) + dbv;
      dt[n * 128 + c] = (v > 20.f) ? v : log1pf(__expf(v));
    }
  }
}

// K4 (phase A): per-chunk P and local scan end, LDS chunk-staged (16 rows/chunk, dbuf)
__global__ __launch_bounds__(512) void k4_scanA(
    const float* __restrict__ dt, const float* __restrict__ xc,
    const float* __restrict__ Bm, const float* __restrict__ Alog,
    float* __restrict__ Pb, float* __restrict__ he)
{
  __shared__ float sdt[2][2048];
  __shared__ float sxc[2][2048];
  __shared__ float sB[2][256];
  const int t = threadIdx.x;
  const int chunk = blockIdx.x;
  const int n0 = chunk * LCH;
  const int srow = t >> 5, scol = (t & 31) * 4;
  const int c = t >> 2, sq = t & 3;
  float4 al = *(const float4*)&Alog[t * 4];
  const float A0 = -__expf(al.x), A1 = -__expf(al.y), A2 = -__expf(al.z), A3 = -__expf(al.w);
  float h0=0,h1=0,h2=0,h3=0;
  float p0=1,p1=1,p2=1,p3=1;

  auto stage = [&](int cb, int buf) {
    int n = n0 + cb * 16 + srow;
    float4 vd = {0,0,0,0}, vx = {0,0,0,0};
    if (n < N_SEQ) {
      vd = *(const float4*)&dt[n * 128 + scol];
      vx = *(const float4*)&xc[n * 128 + scol];
    }
    *(float4*)&sdt[buf][srow * 128 + scol] = vd;
    *(float4*)&sxc[buf][srow * 128 + scol] = vx;
    if (t < 64) {
      int br = t >> 2, bq = (t & 3) * 4;
      int nb = n0 + cb * 16 + br;
      float4 vb = {0,0,0,0};
      if (nb < N_SEQ) vb = *(const float4*)&Bm[nb * 16 + bq];
      *(float4*)&sB[buf][br * 16 + bq] = vb;
    }
  };

  stage(0, 0);
  __syncthreads();
  int cur = 0;
  for (int cb = 0; cb < 4; cb++) {
    if (cb + 1 < 4) stage(cb + 1, cur ^ 1);
    #pragma unroll
    for (int rl = 0; rl < 16; rl++) {
      float dtv = sdt[cur][rl * 128 + c];
      float xv  = sxc[cur][rl * 128 + c];
      float4 Bv = *(const float4*)&sB[cur][rl * 16 + sq * 4];
      float bs = dtv * xv;
      float e0 = __expf(dtv*A0), e1 = __expf(dtv*A1), e2 = __expf(dtv*A2), e3 = __expf(dtv*A3);
      h0 = e0*h0 + bs*Bv.x; h1 = e1*h1 + bs*Bv.y; h2 = e2*h2 + bs*Bv.z; h3 = e3*h3 + bs*Bv.w;
      p0 *= e0; p1 *= e1; p2 *= e2; p3 *= e3;
    }
    __syncthreads();
    cur ^= 1;
  }
  const int base = chunk * 2048 + t * 4;
  float4 P4 = {p0,p1,p2,p3}; *(float4*)&Pb[base] = P4;
  float4 H4 = {h0,h1,h2,h3}; *(float4*)&he[base] = H4;
}

// K5 (phase B): sequential carry over chunks, 8 blocks x 256 threads, 16-deep prefetch.
// NOTE: hi aliases Pb — no __restrict__ here so program-order load/store is kept.
__global__ __launch_bounds__(256) void k5_carry(
    const float* Pb, const float* he, float* hi)
{
  const int q = blockIdx.x * 256 + threadIdx.x;   // chain id, 0..2047
  float pr[PF], er[PF];
  #pragma unroll
  for (int j = 0; j < PF; j++) {
    pr[j] = Pb[j * 2048 + q];
    er[j] = he[j * 2048 + q];
  }
  float h = 0.f;
  for (int k = 0; k < NCH; k += PF) {
    #pragma unroll
    for (int j = 0; j < PF; j++) {
      int kk = k + j;
      if (kk < NCH) {
        hi[kk * 2048 + q] = h;
        h = fmaf(pr[j], h, er[j]);
        int kn = kk + PF;
        if (kn < NCH) {
          pr[j] = Pb[kn * 2048 + q];
          er[j] = he[kn * 2048 + q];
        }
      }
    }
  }
}

// K6 (phase C): replay scan with carries, fused ys*C + D-skip + z-gate -> y
__global__ __launch_bounds__(512) void k6_scanC(
    const float* __restrict__ dt, const float* __restrict__ xc,
    const float* __restrict__ Bm, const float* __restrict__ Cm,
    const float* __restrict__ zs, const float* __restrict__ Alog,
    const float* __restrict__ Dsk, const float* __restrict__ hi,
    float* __restrict__ y)
{
  __shared__ float sdt[2][2048];
  __shared__ float sxc[2][2048];
  __shared__ float szs[2][2048];
  __shared__ float sBC[2][512];
  const int t = threadIdx.x;
  const int chunk = blockIdx.x;
  const int n0 = chunk * LCH;
  const int srow = t >> 5, scol = (t & 31) * 4;
  const int c = t >> 2, sq = t & 3;
  float4 al = *(const float4*)&Alog[t * 4];
  const float A0 = -__expf(al.x), A1 = -__expf(al.y), A2 = -__expf(al.z), A3 = -__expf(al.w);
  float4 h4 = *(const float4*)&hi[chunk * 2048 + t * 4];
  float h0 = h4.x, h1 = h4.y, h2 = h4.z, h3 = h4.w;
  const float Dc = Dsk[c];

  auto stage = [&](int cb, int buf) {
    int n = n0 + cb * 16 + srow;
    float4 vd = {0,0,0,0}, vx = {0,0,0,0}, vz = {0,0,0,0};
    if (n < N_SEQ) {
      vd = *(const float4*)&dt[n * 128 + scol];
      vx = *(const float4*)&xc[n * 128 + scol];
      vz = *(const float4*)&zs[n * 128 + scol];
    }
    *(float4*)&sdt[buf][srow * 128 + scol] = vd;
    *(float4*)&sxc[buf][srow * 128 + scol] = vx;
    *(float4*)&szs[buf][srow * 128 + scol] = vz;
    if (t < 128) {
      int sel = t >> 6;           // 0: B, 1: C
      int u = t & 63;
      int br = u >> 2, bq = (u & 3) * 4;
      int nb = n0 + cb * 16 + br;
      float4 v = {0,0,0,0};
      if (nb < N_SEQ) v = sel ? *(const float4*)&Cm[nb * 16 + bq]
                              : *(const float4*)&Bm[nb * 16 + bq];
      *(float4*)&sBC[buf][sel * 256 + br * 16 + bq] = v;
    }
  };

  stage(0, 0);
  __syncthreads();
  int cur = 0;
  for (int cb = 0; cb < 4; cb++) {
    if (cb + 1 < 4) stage(cb + 1, cur ^ 1);
    #pragma unroll
    for (int rl = 0; rl < 16; rl++) {
      float dtv = sdt[cur][rl * 128 + c];
      float xv  = sxc[cur][rl * 128 + c];
      float zv  = szs[cur][rl * 128 + c];
      float4 Bv = *(const float4*)&sBC[cur][rl * 16 + sq * 4];
      float4 Cv = *(const float4*)&sBC[cur][256 + rl * 16 + sq * 4];
      float bs = dtv * xv;
      float e0 = __expf(dtv*A0), e1 = __expf(dtv*A1), e2 = __expf(dtv*A2), e3 = __expf(dtv*A3);
      h0 = e0*h0 + bs*Bv.x; h1 = e1*h1 + bs*Bv.y; h2 = e2*h2 + bs*Bv.z; h3 = e3*h3 + bs*Bv.w;
      float part = h0*Cv.x + h1*Cv.y + h2*Cv.z + h3*Cv.w;
      part += __shfl_xor(part, 1, 64);
      part += __shfl_xor(part, 2, 64);
      int n = n0 + cb * 16 + rl;
      if (sq == 0 && n < N_SEQ) y[n * 128 + c] = (part + Dc * xv) * zv;
    }
    __syncthreads();
    cur ^= 1;
  }
}

// K6b: feat = y @ out_proj_w.T + feature ; es[n]=exp(logit), per-block sums   [512 threads]
__global__ __launch_bounds__(512) void k6b_out_attn(
    const float* __restrict__ y, const float* __restrict__ ow,
    const float* __restrict__ featg, const float* __restrict__ aw1,
    const float* __restrict__ ab1, const float* __restrict__ aw2,
    const float* __restrict__ ab2, float* __restrict__ es,
    float* __restrict__ absb)
{
  __shared__ float sm[8448 + 8704 + 1088 + 512];
  float* yl  = sm;               // [64][132]
  float* wo  = sm + 8448;        // [128][68], wo[k*68+f] = ow[f*128+k]
  float* aw  = wo + 8704;        // [16][68]
  float* prt = aw + 1088;        // [8][64]
  const int tid = threadIdx.x;
  const int base = blockIdx.x * 64;
  for (int idx = tid; idx < 64 * 128; idx += 512) {
    int r = idx >> 7, k = idx & 127;
    int n = base + r;
    yl[r * 132 + k] = (n < N_SEQ) ? y[n * 128 + k] : 0.f;
  }
  for (int idx = tid; idx < 64 * 128; idx += 512) {
    int f = idx >> 7, k = idx & 127;
    wo[k * 68 + f] = ow[idx];
  }
  for (int idx = tid; idx < 16 * 64; idx += 512) {
    int j = idx >> 6, f = idx & 63;
    aw[j * 68 + f] = aw1[idx];
  }
  __syncthreads();
  const int fg = tid & 15;
  const int rb = tid >> 4;       // rows rb, rb+32
  float acc[2][4];
  #pragma unroll
  for (int i = 0; i < 2; i++) {
    int n = base + rb + 32 * i;
    if (n < N_SEQ) {
      float4 fv = *(const float4*)&featg[n * 64 + fg * 4];
      acc[i][0]=fv.x; acc[i][1]=fv.y; acc[i][2]=fv.z; acc[i][3]=fv.w;
    } else { acc[i][0]=0; acc[i][1]=0; acc[i][2]=0; acc[i][3]=0; }
  }
  #pragma unroll 4
  for (int k = 0; k < 128; k += 4) {
    float4 y0 = *(const float4*)&yl[(rb +  0) * 132 + k];
    float4 y1 = *(const float4*)&yl[(rb + 32) * 132 + k];
    float4 w0 = *(const float4*)&wo[(k + 0) * 68 + fg * 4];
    float4 w1 = *(const float4*)&wo[(k + 1) * 68 + fg * 4];
    float4 w2 = *(const float4*)&wo[(k + 2) * 68 + fg * 4];
    float4 w3 = *(const float4*)&wo[(k + 3) * 68 + fg * 4];
    acc[0][0] += y0.x*w0.x + y0.y*w1.x + y0.z*w2.x + y0.w*w3.x;
    acc[0][1] += y0.x*w0.y + y0.y*w1.y + y0.z*w2.y + y0.w*w3.y;
    acc[0][2] += y0.x*w0.z + y0.y*w1.z + y0.z*w2.z + y0.w*w3.z;
    acc[0][3] += y0.x*w0.w + y0.y*w1.w + y0.z*w2.w + y0.w*w3.w;
    acc[1][0] += y1.x*w0.x + y1.y*w1.x + y1.z*w2.x + y1.w*w3.x;
    acc[1][1] += y1.x*w0.y + y1.y*w1.y + y1.z*w2.y + y1.w*w3.y;
    acc[1][2] += y1.x*w0.z + y1.y*w1.z + y1.z*w2.z + y1.w*w3.z;
    acc[1][3] += y1.x*w0.w + y1.y*w1.w + y1.z*w2.w + y1.w*w3.w;
  }
  __syncthreads();  // all yl reads done before aliasing as feat storage
  float* flds = sm;  // [64][68]
  #pragma unroll
  for (int i = 0; i < 2; i++) {
    int r = rb + 32 * i;
    float4 o = {acc[i][0], acc[i][1], acc[i][2], acc[i][3]};
    *(float4*)&flds[r * 68 + fg * 4] = o;
  }
  __syncthreads();
  const int r = tid & 63, jg = tid >> 6;   // jg 0..7
  float psum = 0.f;
  #pragma unroll
  for (int jj = 0; jj < 2; jj++) {
    int j = jg * 2 + jj;
    float d = ab1[j];
    #pragma unroll
    for (int k = 0; k < 64; k += 4) {
      float4 fv = *(const float4*)&flds[r * 68 + k];
      float4 wv = *(const float4*)&aw[j * 68 + k];
      d += DOT4(fv, wv);
    }
    psum += tanhf(d) * aw2[j];
  }
  prt[jg * 64 + r] = psum;
  __syncthreads();
  if (tid < 64) {
    int n = base + tid;
    float s = ab2[0];
    #pragma unroll
    for (int g = 0; g < 8; g++) s += prt[g * 64 + tid];
    float e = 0.f;
    if (n < N_SEQ) { e = __expf(s); es[n] = e; }
    #pragma unroll
    for (int off = 32; off > 0; off >>= 1) e += __shfl_down(e, off, 64);
    if (tid == 0) absb[blockIdx.x] = e;
  }
}

// K7a: S = sum of per-block exp sums; red[0] = 1/S
__global__ __launch_bounds__(512) void k7a_stats(
    const float* __restrict__ absb, float* __restrict__ red)
{
  __shared__ float sm[512];
  const int t = threadIdx.x;
  sm[t] = (t < NCH) ? absb[t] : 0.f;
  __syncthreads();
  for (int s = 256; s > 0; s >>= 1) { if (t < s) sm[t] += sm[t + s]; __syncthreads(); }
  if (t == 0) red[0] = 1.f / sm[0];
}

// K7b: write A_soft = es*inv and per-block partial M
__global__ __launch_bounds__(256) void k7b_weighted(
    const float* __restrict__ es, const float* __restrict__ featg,
    const float* __restrict__ red, float* __restrict__ out, float* __restrict__ Mp)
{
  __shared__ float prt[4 * 64];
  const int tid = threadIdx.x;
  const int base = blockIdx.x * 256;
  const float inv = red[0];
  const int f = tid & 63, g = tid >> 6;
  float acc = 0.f;
  for (int rr = g; rr < 256; rr += 4) {
    int n = base + rr;
    if (n < N_SEQ) acc += es[n] * inv * featg[n * 64 + f];
  }
  prt[g * 64 + f] = acc;
  int n = base + tid;
  if (n < N_SEQ) out[64 + n] = es[n] * inv;
  __syncthreads();
  if (tid < 64) Mp[blockIdx.x * 64 + tid] = prt[tid] + prt[64 + tid] + prt[128 + tid] + prt[192 + tid];
}

// K7c: M = sum of partials
__global__ __launch_bounds__(64) void k7c_reduceM(
    const float* __restrict__ Mp, float* __restrict__ out)
{
  const int f = threadIdx.x;
  float s = 0.f;
  for (int b = 0; b < NB7; b++) s += Mp[b * 64 + f];
  out[f] = s;
}

extern "C" void kernel_launch(void* const* d_in, const int* in_sizes, int n_in,
                              void* d_out, int out_size, void* d_ws, size_t ws_size,
                              hipStream_t stream)
{
  const float* xp   = (const float*)d_in[0];
  const float* W1   = (const float*)d_in[1];
  const float* b1   = (const float*)d_in[2];
  const float* ipw  = (const float*)d_in[3];
  const float* cw   = (const float*)d_in[4];
  const float* cb   = (const float*)d_in[5];
  const float* xpw  = (const float*)d_in[6];
  const float* dtw  = (const float*)d_in[7];
  const float* dtb  = (const float*)d_in[8];
  const float* Alog = (const float*)d_in[9];
  const float* Dsk  = (const float*)d_in[10];
  const float* ow   = (const float*)d_in[11];
  const float* aw1  = (const float*)d_in[12];
  const float* ab1  = (const float*)d_in[13];
  const float* aw2  = (const float*)d_in[14];
  const float* ab2  = (const float*)d_in[15];

  float* ws = (float*)d_ws;
  float* feature = ws;                       // 1,280,000
  float* xz_x = feature + 1280000;           // 2,560,000 (y alias after k3)
  float* zs   = xz_x + 2560000;              // 2,560,000
  float* xc   = zs + 2560000;                // 2,560,000
  float* dt   = xc + 2560000;                // 2,560,000
  float* Bm   = dt + 2560000;                // 320,000
  float* Cm   = Bm + 320000;                 // 320,000
  float* Pb   = Cm + 320000;                 // 641,024 (hi alias after k5)
  float* he   = Pb + 641024;                 // 641,024
  float* esb  = he + 641024;                 // 20,000 (exp of logits)
  float* absb = esb + 20000;                 // 320 (per-block exp sums)
  float* red  = absb + 320;                  // 16
  float* Mp   = red + 16;                    // 5,056
  ushort* whi = (ushort*)(Mp + 5056);        // 65,536 ushorts
  ushort* wlo = whi + 65536;                 // 65,536 ushorts
  float* part = (float*)(wlo + 65536);       // 2 x 1,280,000 (dedicated)
  float* hi   = Pb;
  float* yv   = xz_x;
  float* out  = (float*)d_out;

  k0_convW<<<256, 256, 0, stream>>>(W1, whi, wlo);
  k1m_mfma<<<dim3(313, 2), 256, 0, stream>>>(xp, whi, wlo, part);
  k1r_reduce<<<1250, 256, 0, stream>>>(part, b1, feature);
  k2_inproj<<<dim3(313, 4), 256, 0, stream>>>(feature, ipw, xz_x, zs);
  k3_conv_proj<<<417, 512, 0, stream>>>(xz_x, cw, cb, xpw, dtw, dtb, xc, dt, Bm, Cm);
  k4_scanA<<<NCH, 512, 0, stream>>>(dt, xc, Bm, Alog, Pb, he);
  k5_carry<<<8, 256, 0, stream>>>(Pb, he, hi);
  k6_scanC<<<NCH, 512, 0, stream>>>(dt, xc, Bm, Cm, zs, Alog, Dsk, hi, yv);
  k6b_out_attn<<<313, 512, 0, stream>>>(yv, ow, feature, aw1, ab1, aw2, ab2, esb, absb);
  k7a_stats<<<1, 512, 0, stream>>>(absb, red);
  k7b_weighted<<<NB7, 256, 0, stream>>>(esb, feature, red, out, Mp);
  k7c_reduceM<<<1, 64, 0, stream>>>(Mp, out);
}